// Round 10
// baseline (80.926 us; speedup 1.0000x reference)
//
#include <hip/hip_runtime.h>

// Problem constants (match reference.py)
#define NB 65536   // trajectories
#define NT 512     // time points (NT-1 steps)

typedef float f32x2 __attribute__((ext_vector_type(2)));
typedef float f32x4 __attribute__((ext_vector_type(4)));

static __device__ __forceinline__ f32x2 fma2(f32x2 a, f32x2 b, f32x2 c) {
    return __builtin_elementwise_fma(a, b, c);   // per-component IEEE fma
}

// 1 trajectory per thread (1 wave/SIMD — fixed TLP budget). Lone-wave walls
// are dependent-LATENCY bound, so this round cuts instructions on the serial
// stream with BITWISE-IDENTICAL math: symmetric b/s ops packed as f32x2
// (v_pk_fma_f32 = same IEEE fma per component, one 2-cyc issue for both).
// Pair-broadcast uniforms {h2,h2},{dt,dt},{h6,h6},{D,D} staged in LDS so no
// per-step broadcast movs. Asymmetric ops (den/rcp/num/rb/ses) stay scalar,
// identical to R9 (absmax must stay exactly 0.0625).
__global__ __launch_bounds__(256) void rk4_biosystem_kernel(
    const float* __restrict__ y0,
    const float* __restrict__ t_eval,
    const float* __restrict__ D_seq,
    const float* __restrict__ K_m_p,
    const float* __restrict__ s_e_p,
    const float* __restrict__ mu_max_p,
    float* __restrict__ out)
{
    __shared__ f32x4 u8[NT][2];   // [t][0]={h2,h2,dt,dt} [t][1]={h6,h6,D,D}; 16 KiB

    const int tid = threadIdx.x;
    for (int i = tid; i < NT; i += 256) {
        const int j = (i < NT - 1) ? i : (NT - 2);   // pad tail (never used)
        const float dt = t_eval[j + 1] - t_eval[j];  // dt exactly as reference
        const float h2 = dt * 0.5f;
        const float h6 = dt * (1.0f / 6.0f);
        const float D  = D_seq[j];
        f32x4 a; a.x = h2; a.y = h2; a.z = dt; a.w = dt;
        f32x4 c; c.x = h6; c.y = h6; c.z = D;  c.w = D;
        u8[i][0] = a;
        u8[i][1] = c;
    }
    __syncthreads();

    const float K_m    = K_m_p[0];
    const float s_e    = s_e_p[0];
    const float mu_max = mu_max_p[0];

    const int traj = blockIdx.x * 256 + tid;

    const f32x2* __restrict__ y0v = (const f32x2*)y0;
    f32x2 y = y0v[traj];                    // (b, s)

    f32x2* __restrict__ out2 = (f32x2*)out; // out[t][traj][2] as vec2
    out2[traj] = y;                         // row 0 = y0
    f32x2* __restrict__ op = out2 + traj;   // walking output pointer

    #pragma unroll 8
    for (int t = 0; t < NT - 1; ++t) {
        const f32x4 ua = u8[t][0];          // {h2,h2,dt,dt}
        const f32x4 uc = u8[t][1];          // {h6,h6,D,D}
        f32x2 h2v; h2v.x = ua.x; h2v.y = ua.y;
        f32x2 dtv; dtv.x = ua.z; dtv.y = ua.w;
        f32x2 h6v; h6v.x = uc.x; h6v.y = uc.y;
        const float D = uc.z;

        // once per step, off the stage chain (scalar, same as R9)
        const float sK  = K_m + y.y;        // K_m + s
        const float ses = s_e - y.y;        // s_e - s
        const float ms  = mu_max * y.y;

        // ---- stage 1 (inputs = y) ----
        const float inv1 = __builtin_amdgcn_rcpf(sK);
        const float rb1  = (ms * y.x) * inv1;
        f32x2 k1;
        k1.x = __builtin_fmaf(-D, y.x, rb1);
        k1.y = __builtin_fmaf(D, ses, -rb1);

        // ---- stage 2 ----
        const f32x2 y2   = fma2(h2v, k1, y);              // packed stage input
        const float den2 = __builtin_fmaf(h2v.x, k1.y, sK);
        const float inv2 = __builtin_amdgcn_rcpf(den2);
        const float rb2  = ((mu_max * y2.y) * y2.x) * inv2;
        f32x2 k2;
        k2.x = __builtin_fmaf(-D, y2.x, rb2);
        k2.y = __builtin_fmaf(D, s_e - y2.y, -rb2);

        // ---- stage 3 ----
        const f32x2 y3   = fma2(h2v, k2, y);
        const float den3 = __builtin_fmaf(h2v.x, k2.y, sK);
        const float inv3 = __builtin_amdgcn_rcpf(den3);
        const float rb3  = ((mu_max * y3.y) * y3.x) * inv3;
        f32x2 k3;
        k3.x = __builtin_fmaf(-D, y3.x, rb3);
        k3.y = __builtin_fmaf(D, s_e - y3.y, -rb3);

        // ---- stage 4 (full dt) ----
        const f32x2 y4   = fma2(dtv, k3, y);
        const float den4 = __builtin_fmaf(dtv.x, k3.y, sK);
        const float inv4 = __builtin_amdgcn_rcpf(den4);
        const float rb4  = ((mu_max * y4.y) * y4.x) * inv4;
        f32x2 k4;
        k4.x = __builtin_fmaf(-D, y4.x, rb4);
        k4.y = __builtin_fmaf(D, s_e - y4.y, -rb4);

        // ---- packed k-sum + update (same per-component ops/order as R9) ----
        const f32x2 t14 = k1 + k4;
        const f32x2 t23 = k2 + k3;
        f32x2 twov; twov.x = 2.0f; twov.y = 2.0f;
        const f32x2 ksum = fma2(twov, t23, t14);
        y = fma2(h6v, ksum, y);

        op += NB;
        *op = y;
    }
}

extern "C" void kernel_launch(void* const* d_in, const int* in_sizes, int n_in,
                              void* d_out, int out_size, void* d_ws, size_t ws_size,
                              hipStream_t stream) {
    const float* y0     = (const float*)d_in[0];
    const float* t_eval = (const float*)d_in[1];
    const float* D_seq  = (const float*)d_in[2];
    const float* K_m    = (const float*)d_in[3];
    const float* s_e    = (const float*)d_in[4];
    const float* mu_max = (const float*)d_in[5];
    float* out = (float*)d_out;

    dim3 grid(NB / 256);
    dim3 block(256);
    rk4_biosystem_kernel<<<grid, block, 0, stream>>>(y0, t_eval, D_seq, K_m, s_e, mu_max, out);
}